// Round 16
// baseline (129.003 us; speedup 1.0000x reference)
//
#include <hip/hip_runtime.h>

// ImageLRU as one GEMM: y[r,:] = W @ x[r,:], W (1024x1024, block-lower-tri)
// built on device. R16: R15 gemm kept VERBATIM; prep fixed.
//   Diagnosis R15: prep_kernel = 75us @ 0.9 TB/s (strided transpose, both
//   sides 128B-segmented + build_w blocks head-blocking the merged grid);
//   gemm is already ~45us. Fix: standalone build_w (8us) + LDS-staged
//   transpose split_x (32 rows x 1024 cols per block; coalesced fp32 reads,
//   padded-LDS transpose, 512B-run tiled writes) ~= 33us memory floor.
//   1-term precision: y = bf16(X)*bf16(W)  (absmax 8192, thr 32768).

namespace {

typedef __attribute__((ext_vector_type(8))) short short8v;
typedef __attribute__((ext_vector_type(4))) float f32x4;

__device__ inline unsigned short f2bf_rne(float f) {
    unsigned u = __builtin_bit_cast(unsigned, f);
    u += 0x7fffu + ((u >> 16) & 1u);
    return (unsigned short)(u >> 16);
}

__device__ inline void gld_lds16(const unsigned short* g, unsigned short* l) {
    __builtin_amdgcn_global_load_lds(
        (const __attribute__((address_space(1))) unsigned int*)g,
        (__attribute__((address_space(3))) unsigned int*)l, 16, 0, 0);
}

// Xh tile ([128 rows][32 k], 4096 ushorts, kg-major): (row,k) at
//   base + ((k>>3)<<10) + (row<<3) + (k&7)
// W  tile ([256 n][32 k], 8192 ushorts, kg-major): (n,k) at
//   base + ((k>>3)<<11) + (n<<3) + (k&7)

// ---------------- prep 1: build Wh (bf16) in [256n][32k] tiles --------------
__global__ __launch_bounds__(256) void build_w_kernel(
    const float* __restrict__ Lre, const float* __restrict__ Lim,
    const float* __restrict__ Bre, const float* __restrict__ Bim,
    const float* __restrict__ Cre, const float* __restrict__ Cim,
    const float* __restrict__ Dm,
    unsigned short* __restrict__ Wh)
{
    const int i = blockIdx.x >> 6, j = blockIdx.x & 63;
    const int t = threadIdx.x, k = t >> 4, l = t & 15;

    const int n_g = i * 16 + k;        // W row (n dim)
    const int k_g = j * 16 + l;        // W col (k dim)
    const size_t widx = (((size_t)((n_g >> 8) * 32 + (k_g >> 5))) << 13)
                      + (((k_g >> 3) & 3) << 11) + ((n_g & 255) << 3) + (k_g & 7);

    if (j > i) { Wh[widx] = 0; return; }

    __shared__ float2 Bs[16][16];
    __shared__ float2 M[16][16];
    Bs[k][l] = make_float2(Bre[t], Bim[t]);
    M[k][l]  = make_float2(k == l ? 1.f : 0.f, 0.f);
    const int delta = i - j;
    __syncthreads();

    #pragma unroll
    for (int d = 0; d < 6; ++d) {
        const int s = 1 << d;
        if (delta & s) {
            const float lr = Lre[k], li = Lim[k];
            const float2 m0 = M[k][l];
            M[k][l] = make_float2(lr * m0.x - li * m0.y, lr * m0.y + li * m0.x);
            __syncthreads();
        } else if (j + (delta & (s - 1)) >= s) {
            float2 acc = make_float2(0.f, 0.f);
            #pragma unroll
            for (int m = 0; m < 16; ++m) {
                const float2 b = Bs[k][m], v = M[m][l];
                acc.x += b.x * v.x - b.y * v.y;
                acc.y += b.x * v.y + b.y * v.x;
            }
            __syncthreads();
            M[k][l] = acc;
            __syncthreads();
        }
    }

    float w = 0.f;
    #pragma unroll
    for (int m = 0; m < 16; ++m) {
        const float2 v = M[m][l];
        w += Cre[k * 16 + m] * v.x - Cim[k * 16 + m] * v.y;
    }
    if (i == j) w += Dm[t];
    Wh[widx] = f2bf_rne(w);
}

// -------- prep 2: X -> Xh tiled, LDS-staged transpose, coalesced both sides -
__global__ __launch_bounds__(256) void split_x_kernel(
    const float* __restrict__ X, unsigned short* __restrict__ Xh)
{
    // 32 rows x 1024 cols per block.
    // LDS image: [kc 0..31](stride 1120) [kg 0..3](stride 264) [row 0..31]x8+h*4
    __shared__ alignas(16) unsigned short s[32 * 1120];   // 71.7 KB

    const int t = threadIdx.x;
    const int r0 = blockIdx.x * 32;          // global row base
    const float* xb = X + ((size_t)r0 << 10);

    // phase 1: coalesced fp32 reads (row p, float4-col t) -> cvt -> LDS
    #pragma unroll 4
    for (int p = 0; p < 32; ++p) {
        const float4 v = *reinterpret_cast<const float4*>(xb + ((size_t)p << 10) + (t << 2));
        ushort4 hv;
        hv.x = f2bf_rne(v.x);
        hv.y = f2bf_rne(v.y);
        hv.z = f2bf_rne(v.z);
        hv.w = f2bf_rne(v.w);
        const int kc = t >> 3, kg = (t >> 1) & 3, h = t & 1;
        *reinterpret_cast<ushort4*>(s + kc * 1120 + kg * 264 + (p << 3) + (h << 2)) = hv;
    }
    __syncthreads();

    // phase 2: LDS b128 reads -> tiled global writes in 512B contiguous runs
    const int mt = r0 >> 7;                  // 128-row tile index
    const int rb = r0 & 127;                 // row base within tile
    #pragma unroll 4
    for (int p = 0; p < 16; ++p) {
        const int slot = p * 256 + t;        // 16B slots, 4096 per block
        const int kc = slot >> 7, kg = (slot >> 5) & 3, row = slot & 31;
        const short8v v = *reinterpret_cast<const short8v*>(
            s + kc * 1120 + kg * 264 + (row << 3));
        *reinterpret_cast<short8v*>(
            Xh + (((size_t)(mt * 32 + kc)) << 12) + (kg << 10) + ((rb + row) << 3)) = v;
    }
}

// ---- main GEMM (R15 verbatim): 128x256, tri-buffer, counted vmcnt(6) -------
__global__ __launch_bounds__(256, 2) void gemm_cnt_kernel(
    const unsigned short* __restrict__ Xh,
    const unsigned short* __restrict__ Wh,
    float* __restrict__ Y, int mtiles)
{
    __shared__ alignas(16) unsigned short sA[3][4096];   // 24 KB
    __shared__ alignas(16) unsigned short sB[3][8192];   // 48 KB

    const int bid = blockIdx.x;
    const int sb = 3 - bid / mtiles;   // 256-col supertile, heavy first (LPT)
    const int mt = bid % mtiles;
    const int t = threadIdx.x;
    const int wid = t >> 6, lane = t & 63;
    const int wr = wid >> 1, wc = wid & 1;     // 2Mx2N wave grid
    const int l15 = lane & 15, lg = lane >> 4;
    const int nt = (sb + 1) * 8;       // K-tiles of 32 (8,16,24,32)

    f32x4 acc[4][8] = {};

    int afo[4], bfo[8];
    #pragma unroll
    for (int mm = 0; mm < 4; ++mm)
        afo[mm] = (lg << 10) + ((wr * 64 + mm * 16 + l15) << 3);
    #pragma unroll
    for (int nn = 0; nn < 8; ++nn)
        bfo[nn] = (lg << 11) + ((wc * 128 + nn * 16 + l15) << 3);

    auto stageT = [&](int b3, int tk) {        // 6 gld_lds16 per thread
        unsigned short* bA = sA[b3];
        unsigned short* bB = sB[b3];
        const unsigned short* xa = Xh + (((size_t)(mt * 32 + tk)) << 12);
        const unsigned short* wb = Wh + (((size_t)(sb * 32 + tk)) << 13);
        gld_lds16(xa + t * 8,        bA + t * 8);
        gld_lds16(xa + 2048 + t * 8, bA + 2048 + t * 8);
        gld_lds16(wb + t * 8,        bB + t * 8);
        gld_lds16(wb + 2048 + t * 8, bB + 2048 + t * 8);
        gld_lds16(wb + 4096 + t * 8, bB + 4096 + t * 8);
        gld_lds16(wb + 6144 + t * 8, bB + 6144 + t * 8);
    };

    stageT(0, 0);
    stageT(1, 1);
    asm volatile("s_waitcnt vmcnt(6)" ::: "memory");
    __builtin_amdgcn_sched_barrier(0);
    __builtin_amdgcn_s_barrier();
    __builtin_amdgcn_sched_barrier(0);

    int c = 0, c2 = 2;                 // tk%3, (tk+2)%3
    for (int tk = 0; tk < nt; ++tk) {
        if (tk + 2 < nt) stageT(c2, tk + 2);

        short8v ah[4], bh[8];
        #pragma unroll
        for (int mm = 0; mm < 4; ++mm)
            ah[mm] = *reinterpret_cast<const short8v*>(sA[c] + afo[mm]);
        #pragma unroll
        for (int nn = 0; nn < 8; ++nn)
            bh[nn] = *reinterpret_cast<const short8v*>(sB[c] + bfo[nn]);

        __builtin_amdgcn_s_setprio(1);
        #pragma unroll
        for (int mm = 0; mm < 4; ++mm)
            #pragma unroll
            for (int nn = 0; nn < 8; ++nn)
                acc[mm][nn] = __builtin_amdgcn_mfma_f32_16x16x32_bf16(
                    ah[mm], bh[nn], acc[mm][nn], 0, 0, 0);
        __builtin_amdgcn_s_setprio(0);

        if (tk + 1 < nt) {             // tile boundary
            if (tk + 2 < nt) {
                asm volatile("s_waitcnt vmcnt(6)" ::: "memory");
            } else {
                asm volatile("s_waitcnt vmcnt(0)" ::: "memory");
            }
            __builtin_amdgcn_sched_barrier(0);
            __builtin_amdgcn_s_barrier();
            __builtin_amdgcn_sched_barrier(0);
        }
        c = (c == 2) ? 0 : c + 1;
        c2 = (c2 == 2) ? 0 : c2 + 1;
    }

    // ---- epilogue: C/D layout col=lane&15, row=(lane>>4)*4+q ----
    #pragma unroll
    for (int mm = 0; mm < 4; ++mm) {
        const int grow = mt * 128 + wr * 64 + mm * 16 + lg * 4;
        #pragma unroll
        for (int nn = 0; nn < 8; ++nn) {
            const int gcol = sb * 256 + wc * 128 + nn * 16 + l15;
            #pragma unroll
            for (int q = 0; q < 4; ++q)
                Y[(size_t)(grow + q) * 1024 + gcol] = acc[mm][nn][q];
        }
    }
}

} // namespace

extern "C" void kernel_launch(void* const* d_in, const int* in_sizes, int n_in,
                              void* d_out, int out_size, void* d_ws, size_t ws_size,
                              hipStream_t stream) {
    const float* x   = (const float*)d_in[0];
    const float* Lre = (const float*)d_in[1];
    const float* Lim = (const float*)d_in[2];
    const float* Bre = (const float*)d_in[3];
    const float* Bim = (const float*)d_in[4];
    const float* Cre = (const float*)d_in[5];
    const float* Cim = (const float*)d_in[6];
    const float* Dm  = (const float*)d_in[7];
    float* y = (float*)d_out;

    const int positions = in_sizes[0] / 1024;          // 32768
    const int mtiles = positions / 128;                // 256

    unsigned short* Wh = (unsigned short*)d_ws;        // 2 MB
    unsigned short* Xh = Wh + 1024 * 1024;             // 64 MB

    build_w_kernel<<<4096, 256, 0, stream>>>(Lre, Lim, Bre, Bim, Cre, Cim, Dm, Wh);
    split_x_kernel<<<positions / 32, 256, 0, stream>>>(x, Xh);
    gemm_cnt_kernel<<<mtiles * 4, 256, 0, stream>>>(Xh, Wh, y, mtiles);
}

// Round 17
// 125.275 us; speedup vs baseline: 1.0298x; 1.0298x over previous
//
#include <hip/hip_runtime.h>

// ImageLRU as one GEMM: y[r,:] = W @ x[r,:], W (1024x1024, block-lower-tri)
// built on device. R17: NO transpose anywhere.
//   - Xh is ROW-MAJOR bf16, written by a pure streaming cast (trivial
//     coalescing, ~33us) fused into the prep launch with build_w.
//   - gemm = R15 tri-buffer counted-vmcnt skeleton; A staged by gld_lds with
//     PER-LANE row-major sources (dest stays linear t*16 -> LDS image is
//     row-major [128][64B]). A-frag ds_reads accept an 8-way bank conflict
//     (~+90cy/tile/wave vs 256cy MFMA) -- cheaper than any transpose pass.
//   - W unchanged: kg-major [256n][32k] tiles, L2-resident, conflict-free.
//   1-term precision: y = bf16(X)*bf16(W)  (absmax 8192, thr 32768).

namespace {

typedef __attribute__((ext_vector_type(8))) short short8v;
typedef __attribute__((ext_vector_type(4))) float f32x4;

__device__ inline unsigned short f2bf_rne(float f) {
    unsigned u = __builtin_bit_cast(unsigned, f);
    u += 0x7fffu + ((u >> 16) & 1u);
    return (unsigned short)(u >> 16);
}

__device__ inline void gld_lds16(const unsigned short* g, unsigned short* l) {
    __builtin_amdgcn_global_load_lds(
        (const __attribute__((address_space(1))) unsigned int*)g,
        (__attribute__((address_space(3))) unsigned int*)l, 16, 0, 0);
}

// W tile ([256 n][32 k], 8192 ushorts, kg-major): (n,k) at
//   base + ((k>>3)<<11) + (n<<3) + (k&7)
// Xh: plain row-major [32768][1024] bf16.

// ------- prep: blocks [0,4096) build W; [4096,6144) stream-cast X ----------
__global__ __launch_bounds__(256) void prep_kernel(
    const float* __restrict__ X,
    const float* __restrict__ Lre, const float* __restrict__ Lim,
    const float* __restrict__ Bre, const float* __restrict__ Bim,
    const float* __restrict__ Cre, const float* __restrict__ Cim,
    const float* __restrict__ Dm,
    unsigned short* __restrict__ Wh, unsigned short* __restrict__ Xh)
{
    const int t = threadIdx.x;

    if (blockIdx.x >= 4096) {
        // ---- streaming cast: 2048 blocks x 256 t x 8 chunks of 8 floats ----
        const int sid = blockIdx.x - 4096;
        #pragma unroll
        for (int p = 0; p < 8; ++p) {
            const size_t c8 = ((size_t)p * 2048 * 256 + (size_t)sid * 256 + t) * 8;
            const float4 a = *reinterpret_cast<const float4*>(X + c8);
            const float4 b = *reinterpret_cast<const float4*>(X + c8 + 4);
            short8v hv;
            hv[0] = (short)f2bf_rne(a.x); hv[1] = (short)f2bf_rne(a.y);
            hv[2] = (short)f2bf_rne(a.z); hv[3] = (short)f2bf_rne(a.w);
            hv[4] = (short)f2bf_rne(b.x); hv[5] = (short)f2bf_rne(b.y);
            hv[6] = (short)f2bf_rne(b.z); hv[7] = (short)f2bf_rne(b.w);
            *reinterpret_cast<short8v*>(Xh + c8) = hv;
        }
        return;
    }

    // ---- build W block (i,j): T = prod of stage factors; W = Re(C*T)+D ----
    const int i = blockIdx.x >> 6, j = blockIdx.x & 63;
    const int k = t >> 4, l = t & 15;

    const int n_g = i * 16 + k;        // W row (n dim)
    const int k_g = j * 16 + l;        // W col (k dim)
    const size_t widx = (((size_t)((n_g >> 8) * 32 + (k_g >> 5))) << 13)
                      + (((k_g >> 3) & 3) << 11) + ((n_g & 255) << 3) + (k_g & 7);

    if (j > i) { Wh[widx] = 0; return; }

    __shared__ float2 Bs[16][16];
    __shared__ float2 M[16][16];
    Bs[k][l] = make_float2(Bre[t], Bim[t]);
    M[k][l]  = make_float2(k == l ? 1.f : 0.f, 0.f);
    const int delta = i - j;
    __syncthreads();

    #pragma unroll
    for (int d = 0; d < 6; ++d) {
        const int s = 1 << d;
        if (delta & s) {
            const float lr = Lre[k], li = Lim[k];
            const float2 m0 = M[k][l];
            M[k][l] = make_float2(lr * m0.x - li * m0.y, lr * m0.y + li * m0.x);
            __syncthreads();
        } else if (j + (delta & (s - 1)) >= s) {
            float2 acc = make_float2(0.f, 0.f);
            #pragma unroll
            for (int m = 0; m < 16; ++m) {
                const float2 b = Bs[k][m], v = M[m][l];
                acc.x += b.x * v.x - b.y * v.y;
                acc.y += b.x * v.y + b.y * v.x;
            }
            __syncthreads();
            M[k][l] = acc;
            __syncthreads();
        }
    }

    float w = 0.f;
    #pragma unroll
    for (int m = 0; m < 16; ++m) {
        const float2 v = M[m][l];
        w += Cre[k * 16 + m] * v.x - Cim[k * 16 + m] * v.y;
    }
    if (i == j) w += Dm[t];
    Wh[widx] = f2bf_rne(w);
}

// ---- main GEMM: 128x256, tri-buffer, counted vmcnt(6), row-major A source --
__global__ __launch_bounds__(256, 2) void gemm_cnt_kernel(
    const unsigned short* __restrict__ Xh,
    const unsigned short* __restrict__ Wh,
    float* __restrict__ Y, int mtiles)
{
    __shared__ alignas(16) unsigned short sA[3][4096];   // 24 KB
    __shared__ alignas(16) unsigned short sB[3][8192];   // 48 KB

    const int bid = blockIdx.x;
    const int sb = 3 - bid / mtiles;   // 256-col supertile, heavy first (LPT)
    const int mt = bid % mtiles;
    const int t = threadIdx.x;
    const int wid = t >> 6, lane = t & 63;
    const int wr = wid >> 1, wc = wid & 1;     // 2Mx2N wave grid
    const int l15 = lane & 15, lg = lane >> 4;
    const int nt = (sb + 1) * 8;       // K-tiles of 32 (8,16,24,32)

    f32x4 acc[4][8] = {};

    // A-frag offsets in row-major LDS image [128 rows][32 k]:
    //   (row, k=lg*8..) at (row*32 + lg*8) ushorts
    int afo[4], bfo[8];
    #pragma unroll
    for (int mm = 0; mm < 4; ++mm)
        afo[mm] = ((wr * 64 + mm * 16 + l15) << 5) + (lg << 3);
    #pragma unroll
    for (int nn = 0; nn < 8; ++nn)
        bfo[nn] = (lg << 11) + ((wc * 128 + nn * 16 + l15) << 3);

    // per-lane A source offsets (ushorts) for the two staged slots:
    //   slot s = t / 256+t: row = s>>2, kq = s&3
    const int arow0 = t >> 2, akq = t & 3;
    const size_t asrc0 = (size_t)arow0 * 1024 + akq * 8;
    const size_t asrc1 = (size_t)(64 + arow0) * 1024 + akq * 8;

    auto stageT = [&](int b3, int tk) {        // 6 gld_lds16 per thread
        unsigned short* bA = sA[b3];
        unsigned short* bB = sB[b3];
        const unsigned short* xa = Xh + ((size_t)mt << 17) + tk * 32;  // mt*128*1024
        const unsigned short* wb = Wh + (((size_t)(sb * 32 + tk)) << 13);
        gld_lds16(xa + asrc0, bA + t * 8);
        gld_lds16(xa + asrc1, bA + 2048 + t * 8);
        gld_lds16(wb + t * 8,        bB + t * 8);
        gld_lds16(wb + 2048 + t * 8, bB + 2048 + t * 8);
        gld_lds16(wb + 4096 + t * 8, bB + 4096 + t * 8);
        gld_lds16(wb + 6144 + t * 8, bB + 6144 + t * 8);
    };

    stageT(0, 0);
    stageT(1, 1);
    asm volatile("s_waitcnt vmcnt(6)" ::: "memory");
    __builtin_amdgcn_sched_barrier(0);
    __builtin_amdgcn_s_barrier();
    __builtin_amdgcn_sched_barrier(0);

    int c = 0, c2 = 2;                 // tk%3, (tk+2)%3
    for (int tk = 0; tk < nt; ++tk) {
        if (tk + 2 < nt) stageT(c2, tk + 2);

        short8v ah[4], bh[8];
        #pragma unroll
        for (int mm = 0; mm < 4; ++mm)
            ah[mm] = *reinterpret_cast<const short8v*>(sA[c] + afo[mm]);
        #pragma unroll
        for (int nn = 0; nn < 8; ++nn)
            bh[nn] = *reinterpret_cast<const short8v*>(sB[c] + bfo[nn]);

        __builtin_amdgcn_s_setprio(1);
        #pragma unroll
        for (int mm = 0; mm < 4; ++mm)
            #pragma unroll
            for (int nn = 0; nn < 8; ++nn)
                acc[mm][nn] = __builtin_amdgcn_mfma_f32_16x16x32_bf16(
                    ah[mm], bh[nn], acc[mm][nn], 0, 0, 0);
        __builtin_amdgcn_s_setprio(0);

        if (tk + 1 < nt) {             // tile boundary
            if (tk + 2 < nt) {
                asm volatile("s_waitcnt vmcnt(6)" ::: "memory");
            } else {
                asm volatile("s_waitcnt vmcnt(0)" ::: "memory");
            }
            __builtin_amdgcn_sched_barrier(0);
            __builtin_amdgcn_s_barrier();
            __builtin_amdgcn_sched_barrier(0);
        }
        c = (c == 2) ? 0 : c + 1;
        c2 = (c2 == 2) ? 0 : c2 + 1;
    }

    // ---- epilogue: C/D layout col=lane&15, row=(lane>>4)*4+q ----
    #pragma unroll
    for (int mm = 0; mm < 4; ++mm) {
        const int grow = mt * 128 + wr * 64 + mm * 16 + lg * 4;
        #pragma unroll
        for (int nn = 0; nn < 8; ++nn) {
            const int gcol = sb * 256 + wc * 128 + nn * 16 + l15;
            #pragma unroll
            for (int q = 0; q < 4; ++q)
                Y[(size_t)(grow + q) * 1024 + gcol] = acc[mm][nn][q];
        }
    }
}

} // namespace

extern "C" void kernel_launch(void* const* d_in, const int* in_sizes, int n_in,
                              void* d_out, int out_size, void* d_ws, size_t ws_size,
                              hipStream_t stream) {
    const float* x   = (const float*)d_in[0];
    const float* Lre = (const float*)d_in[1];
    const float* Lim = (const float*)d_in[2];
    const float* Bre = (const float*)d_in[3];
    const float* Bim = (const float*)d_in[4];
    const float* Cre = (const float*)d_in[5];
    const float* Cim = (const float*)d_in[6];
    const float* Dm  = (const float*)d_in[7];
    float* y = (float*)d_out;

    const int positions = in_sizes[0] / 1024;          // 32768
    const int mtiles = positions / 128;                // 256

    unsigned short* Wh = (unsigned short*)d_ws;        // 2 MB
    unsigned short* Xh = Wh + 1024 * 1024;             // 64 MB

    prep_kernel<<<4096 + 2048, 256, 0, stream>>>(
        x, Lre, Lim, Bre, Bim, Cre, Cim, Dm, Wh, Xh);
    gemm_cnt_kernel<<<mtiles * 4, 256, 0, stream>>>(Xh, Wh, y, mtiles);
}

// Round 18
// 96.264 us; speedup vs baseline: 1.3401x; 1.3014x over previous
//
#include <hip/hip_runtime.h>

// ImageLRU as one GEMM: y[r,:] = W @ x[r,:], W (1024x1024, block-lower-tri)
// built on device. R18: cast fused INTO the GEMM, no Xh intermediate.
//  - A staged as RAW fp32 from row-major X via global_load_lds with per-lane
//    PRE-SWIZZLED sources: slot (row,kq) fetches chunk kq^(row&7); LDS dest
//    lane-linear (m173/m201 both-sides-or-neither). Frag reads use the same
//    XOR -> uniform banks (2 lanes/bank, free). fp32->bf16 RNE at frag time.
//  - No ds_write (R5 bug gone), nb-major LPT (R10 FETCH blowup gone), no
//    VGPR roundtrip for A (R12 serialization gone).
//  - BM=128 x BN=256, 4 waves (2Mx2N, acc[4][8], 32 MFMA/tile/wave), dbuf
//    (A 16KB fp32 + B 16KB bf16) x2 = 64 KB -> 2 blocks/CU, R4-proven
//    stage->compute->barrier skeleton, setprio on MFMA cluster.
//  - build_w now the only prep: its true cost becomes measurable.
//  1-term precision: y = bf16(X)*bf16(W)  (absmax 8192, thr 32768).

namespace {

typedef __attribute__((ext_vector_type(8))) short short8v;
typedef __attribute__((ext_vector_type(4))) float f32x4;

__device__ inline unsigned short f2bf_rne(float f) {
    unsigned u = __builtin_bit_cast(unsigned, f);
    u += 0x7fffu + ((u >> 16) & 1u);
    return (unsigned short)(u >> 16);
}

__device__ inline void gld_lds16(const unsigned short* g, unsigned short* l) {
    __builtin_amdgcn_global_load_lds(
        (const __attribute__((address_space(1))) unsigned int*)g,
        (__attribute__((address_space(3))) unsigned int*)l, 16, 0, 0);
}

// W tile ([256 n][32 k], 8192 ushorts, kg-major): (n,k) at
//   base + ((k>>3)<<11) + (n<<3) + (k&7)        [R15-proven conflict-free]
// A LDS tile: fp32 [128 rows][32 k], row-major, 16B chunk kq stored at
//   slot (row, kq^(row&7))  -> frag reads bank-uniform.

// ---------------- prep: build Wh (bf16) in [256n][32k] tiles ----------------
__global__ __launch_bounds__(256) void build_w_kernel(
    const float* __restrict__ Lre, const float* __restrict__ Lim,
    const float* __restrict__ Bre, const float* __restrict__ Bim,
    const float* __restrict__ Cre, const float* __restrict__ Cim,
    const float* __restrict__ Dm,
    unsigned short* __restrict__ Wh)
{
    const int i = blockIdx.x >> 6, j = blockIdx.x & 63;
    const int t = threadIdx.x, k = t >> 4, l = t & 15;

    const int n_g = i * 16 + k;        // W row (n dim)
    const int k_g = j * 16 + l;        // W col (k dim)
    const size_t widx = (((size_t)((n_g >> 8) * 32 + (k_g >> 5))) << 13)
                      + (((k_g >> 3) & 3) << 11) + ((n_g & 255) << 3) + (k_g & 7);

    if (j > i) { Wh[widx] = 0; return; }

    __shared__ float2 Bs[16][16];
    __shared__ float2 M[16][16];
    Bs[k][l] = make_float2(Bre[t], Bim[t]);
    M[k][l]  = make_float2(k == l ? 1.f : 0.f, 0.f);
    const int delta = i - j;
    __syncthreads();

    #pragma unroll
    for (int d = 0; d < 6; ++d) {
        const int s = 1 << d;
        if (delta & s) {
            const float lr = Lre[k], li = Lim[k];
            const float2 m0 = M[k][l];
            M[k][l] = make_float2(lr * m0.x - li * m0.y, lr * m0.y + li * m0.x);
            __syncthreads();
        } else if (j + (delta & (s - 1)) >= s) {
            float2 acc = make_float2(0.f, 0.f);
            #pragma unroll
            for (int m = 0; m < 16; ++m) {
                const float2 b = Bs[k][m], v = M[m][l];
                acc.x += b.x * v.x - b.y * v.y;
                acc.y += b.x * v.y + b.y * v.x;
            }
            __syncthreads();
            M[k][l] = acc;
            __syncthreads();
        }
    }

    float w = 0.f;
    #pragma unroll
    for (int m = 0; m < 16; ++m) {
        const float2 v = M[m][l];
        w += Cre[k * 16 + m] * v.x - Cim[k * 16 + m] * v.y;
    }
    if (i == j) w += Dm[t];
    Wh[widx] = f2bf_rne(w);
}

// ------ main GEMM: fused cvt, A fp32 swizzle-staged, 128x256, dbuf ----------
__global__ __launch_bounds__(256) void gemm_fused_kernel(
    const float* __restrict__ X,
    const unsigned short* __restrict__ Wh,
    float* __restrict__ Y, int mtiles)
{
    __shared__ alignas(16) float sA[2][4096];            // 2 x 16 KB fp32
    __shared__ alignas(16) unsigned short sB[2][8192];   // 2 x 16 KB bf16

    const int bid = blockIdx.x;
    const int sb = 3 - bid / mtiles;   // 256-col supertile, heavy first (LPT)
    const int mt = bid % mtiles;
    const int t = threadIdx.x;
    const int wid = t >> 6, lane = t & 63;
    const int wr = wid >> 1, wc = wid & 1;     // 2Mx2N wave grid
    const int l15 = lane & 15, lg = lane >> 4;
    const int nt = (sb + 1) * 8;       // K-tiles of 32

    f32x4 acc[4][8] = {};

    // A staging source offsets (per-lane, pre-swizzled)
    // slot s = p*256+t: row = s>>3, kq = s&7; fetch chunk kq^(row&7)
    // A frag read offsets (floats): row*32 + swz*4
    int arow[4], as0[4], as1[4];
    #pragma unroll
    for (int mm = 0; mm < 4; ++mm) {
        const int row = wr * 64 + mm * 16 + l15;
        arow[mm] = row << 5;
        as0[mm] = (((2 * lg)     ^ (row & 7)) << 2);
        as1[mm] = (((2 * lg + 1) ^ (row & 7)) << 2);
    }
    // B frag offsets (ushorts) within a W tile
    int bfo[8];
    #pragma unroll
    for (int nn = 0; nn < 8; ++nn)
        bfo[nn] = (lg << 11) + ((wc * 128 + nn * 16 + l15) << 3);

    auto stageT = [&](int b, int tk) {         // 8 gld_lds16 per thread
        float* bA = sA[b];
        unsigned short* bB = sB[b];
        const float* xbase = X + (size_t)mt * 131072 + tk * 32;  // mt*128*1024
        #pragma unroll
        for (int p = 0; p < 4; ++p) {
            const int s = p * 256 + t;
            const int row = s >> 3, kq = s & 7;
            const float* src = xbase + (size_t)row * 1024 + ((kq ^ (row & 7)) << 2);
            gld_lds16((const unsigned short*)src, (unsigned short*)(bA + s * 4));
        }
        const unsigned short* wb = Wh + (((size_t)(sb * 32 + tk)) << 13);
        #pragma unroll
        for (int p = 0; p < 4; ++p) {
            const int e8 = (p * 256 + t) * 8;
            gld_lds16(wb + e8, bB + e8);
        }
    };

    stageT(0, 0);
    __syncthreads();                   // buf0 ready (implicit vmcnt drain)

    for (int tk = 0; tk < nt; ++tk) {
        const int c = tk & 1;
        if (tk + 1 < nt) stageT(c ^ 1, tk + 1);   // DMA in flight across MFMA

        // A fragments: fp32 LDS reads (swizzled, bank-uniform) + RNE cvt
        short8v ah[4];
        #pragma unroll
        for (int mm = 0; mm < 4; ++mm) {
            const f32x4 q0 = *reinterpret_cast<const f32x4*>(sA[c] + arow[mm] + as0[mm]);
            const f32x4 q1 = *reinterpret_cast<const f32x4*>(sA[c] + arow[mm] + as1[mm]);
            short8v r;
            r[0] = (short)f2bf_rne(q0[0]); r[1] = (short)f2bf_rne(q0[1]);
            r[2] = (short)f2bf_rne(q0[2]); r[3] = (short)f2bf_rne(q0[3]);
            r[4] = (short)f2bf_rne(q1[0]); r[5] = (short)f2bf_rne(q1[1]);
            r[6] = (short)f2bf_rne(q1[2]); r[7] = (short)f2bf_rne(q1[3]);
            ah[mm] = r;
        }
        short8v bh[8];
        #pragma unroll
        for (int nn = 0; nn < 8; ++nn)
            bh[nn] = *reinterpret_cast<const short8v*>(sB[c] + bfo[nn]);

        __builtin_amdgcn_s_setprio(1);
        #pragma unroll
        for (int mm = 0; mm < 4; ++mm)
            #pragma unroll
            for (int nn = 0; nn < 8; ++nn)
                acc[mm][nn] = __builtin_amdgcn_mfma_f32_16x16x32_bf16(
                    ah[mm], bh[nn], acc[mm][nn], 0, 0, 0);
        __builtin_amdgcn_s_setprio(0);

        __syncthreads();   // readers of buf c done; buf c^1 DMA landed
    }

    // ---- epilogue: C/D layout col=lane&15, row=(lane>>4)*4+q ----
    #pragma unroll
    for (int mm = 0; mm < 4; ++mm) {
        const int grow = mt * 128 + wr * 64 + mm * 16 + lg * 4;
        #pragma unroll
        for (int nn = 0; nn < 8; ++nn) {
            const int gcol = sb * 256 + wc * 128 + nn * 16 + l15;
            #pragma unroll
            for (int q = 0; q < 4; ++q)
                Y[(size_t)(grow + q) * 1024 + gcol] = acc[mm][nn][q];
        }
    }
}

} // namespace

extern "C" void kernel_launch(void* const* d_in, const int* in_sizes, int n_in,
                              void* d_out, int out_size, void* d_ws, size_t ws_size,
                              hipStream_t stream) {
    const float* x   = (const float*)d_in[0];
    const float* Lre = (const float*)d_in[1];
    const float* Lim = (const float*)d_in[2];
    const float* Bre = (const float*)d_in[3];
    const float* Bim = (const float*)d_in[4];
    const float* Cre = (const float*)d_in[5];
    const float* Cim = (const float*)d_in[6];
    const float* Dm  = (const float*)d_in[7];
    float* y = (float*)d_out;

    const int positions = in_sizes[0] / 1024;          // 32768
    const int mtiles = positions / 128;                // 256

    unsigned short* Wh = (unsigned short*)d_ws;        // 2 MB

    build_w_kernel<<<4096, 256, 0, stream>>>(Lre, Lim, Bre, Bim, Cre, Cim, Dm, Wh);
    gemm_fused_kernel<<<mtiles * 4, 256, 0, stream>>>(x, Wh, y, mtiles);
}